// Round 15
// baseline (461.422 us; speedup 1.0000x reference)
//
#include <hip/hip_runtime.h>

#define N_NODES 50000
#define N_EDGES 1600000
#define F_IN 1433
#define HID 128
#define NCLS 7
#define KSTEPS 45

// ---- workspace layout (bytes), all 256-aligned ----
#define O_DEG_SRC 0u          // N ints   (200000)
#define O_DEG_DST 200704u     // N ints
#define O_CURSOR  401408u     // N ints
#define O_ROWPTR  602112u     // N+1 ints
#define O_NSRC    802816u     // N floats
#define O_NDST    1003520u    // N floats
#define O_BSUM    1204224u    // 256 ints
#define O_BOFF    1205248u    // 256 ints
#define O_CSR     1206272u    // E ints (6400000)
#define O_H       7606272u    // N*128 _Float16 (12800000), 16B aligned
#define O_H2      33206272u   // N*8 floats padded (1600000)
#define O_W1S     34806272u   // 45*4096 _Float16 = 368640 B (fp16, staged layout)

typedef __attribute__((ext_vector_type(4))) float f4v;       // 4 f32
typedef __attribute__((ext_vector_type(8))) _Float16 h8v;    // 8 fp16 (16B, 4 VGPRs)
typedef __attribute__((ext_vector_type(4))) _Float16 h4v;    // 4 fp16 (8B)

__global__ void zero_ws_kernel(int4* __restrict__ p) {
    int i = blockIdx.x * 256 + threadIdx.x;
    if (i < 37632) p[i] = make_int4(0, 0, 0, 0);
}

__global__ void deg_kernel(const int* __restrict__ dst, int* __restrict__ deg_dst) {
    int e = blockIdx.x * blockDim.x + threadIdx.x;
    if (e < N_EDGES) atomicAdd(&deg_dst[dst[e]], 1);
}

__global__ void scan1_kernel(const int* __restrict__ deg, int* __restrict__ incl,
                             int* __restrict__ bsum) {
    __shared__ int s[256];
    int t = threadIdx.x;
    int i = blockIdx.x * 256 + t;
    int v = (i < N_NODES) ? deg[i] : 0;
    s[t] = v;
    __syncthreads();
    for (int off = 1; off < 256; off <<= 1) {
        int a = (t >= off) ? s[t - off] : 0;
        __syncthreads();
        s[t] += a;
        __syncthreads();
    }
    if (i < N_NODES) incl[i] = s[t];
    if (t == 255) bsum[blockIdx.x] = s[255];
}

__global__ void scan2_kernel(const int* __restrict__ bsum, int* __restrict__ boff, int nb) {
    __shared__ int s[256];
    int t = threadIdx.x;
    int v = (t < nb) ? bsum[t] : 0;
    s[t] = v;
    __syncthreads();
    for (int off = 1; off < 256; off <<= 1) {
        int a = (t >= off) ? s[t - off] : 0;
        __syncthreads();
        s[t] += a;
        __syncthreads();
    }
    if (t < nb) boff[t] = s[t] - v;  // exclusive
}

__global__ void scan3_kernel(int* __restrict__ rowptr, const int* __restrict__ deg_dst,
                             const int* __restrict__ boff, float* __restrict__ ndst) {
    int i = blockIdx.x * 256 + threadIdx.x;
    if (i < N_NODES) {
        int dd = deg_dst[i];
        rowptr[i] = rowptr[i] - dd + boff[blockIdx.x];
        ndst[i] = rsqrtf(fmaxf((float)dd, 1.0f));
    }
}

__global__ void fill_kernel(const int* __restrict__ src, const int* __restrict__ dst,
                            const int* __restrict__ rowptr, int* __restrict__ cursor,
                            int* __restrict__ csr, int* __restrict__ deg_src) {
    int e = blockIdx.x * blockDim.x + threadIdx.x;
    if (e < N_EDGES) {
        int s = src[e];
        int d = dst[e];
        atomicAdd(&deg_src[s], 1);
        int pos = rowptr[d] + atomicAdd(&cursor[d], 1);
        csr[pos] = s;
    }
}

__global__ void nsrc_kernel(const int* __restrict__ deg_src, float* __restrict__ nsrc) {
    int i = blockIdx.x * 256 + threadIdx.x;
    if (i < N_NODES) nsrc[i] = rsqrtf(fmaxf((float)deg_src[i], 1.0f));
}

// ---- W1 prep: fp16, staged granule order ----
// W1S[s*4096 + (k4*128 + n)*8 + j] = (fp16) W1[s*32 + k4*8 + j][n], zero-pad k>=F_IN
__global__ void w1prep_kernel(const float* __restrict__ W1, _Float16* __restrict__ W1S) {
    int t = blockIdx.x * 256 + threadIdx.x;  // (s*4 + k4)*128 + n, total 23040
    if (t >= KSTEPS * 4 * 128) return;
    int n = t & 127;
    int k4 = (t >> 7) & 3;
    int s = t >> 9;
    long base = (long)s * 4096 + (k4 * 128 + n) * 8;
#pragma unroll
    for (int j = 0; j < 8; j++) {
        int k = s * 32 + k4 * 8 + j;
        W1S[base + j] = (_Float16)((k < F_IN) ? W1[(long)k * HID + n] : 0.f);
    }
}

// ---- GEMM1: h = nsrc[:,None] * (X @ W1), fp16 MFMA, fp16 out ----
// GBM=16: whole A-panel (16 rows x 1433 f32) staged ONCE into LDS as fp16
// (dense sequential per-row streams, 90 loads/thread in flight), then a
// BARRIER-FREE 45-step K-loop: 1 ds_read_b128 + 2 L2 B-loads + 2 MFMA per
// step per wave. nsrc applied in the f32 epilogue (diag-scale commutes).
#define GBM 16
#define RST 1448  // LDS row stride in fp16 elems (2896 B -> <=2-way bank aliasing)
__global__ __launch_bounds__(256, 8) void gemm1_mfma_kernel(const float* __restrict__ X,
                                                            const _Float16* __restrict__ W1S,
                                                            const float* __restrict__ nsrc,
                                                            _Float16* __restrict__ h) {
    __shared__ __align__(16) _Float16 xs[GBM * RST];  // 46336 B
    const int tid = threadIdx.x;
    const int l = tid & 63;
    const int w = tid >> 6;   // wave id -> col group w*32
    const int k4r = l >> 4;
    const int l15 = l & 15;
    const int bm = blockIdx.x * GBM;  // grid 3125 * 16 = 50000 exact

    // ---- stage: 16 threads/row, each reads a dense sequential sub-stream ----
    {
        const int sr = tid >> 4;   // row 0..15
        const int sc = tid & 15;   // chunk lane within row
        const float* Xr = X + (long)(bm + sr) * F_IN;
        _Float16* dst = xs + sr * RST;
        // 360 quads of 4 floats per row; chunk c = sc + 16*i
#pragma unroll 4
        for (int i = 0; i < 23; ++i) {
            int c = sc + 16 * i;
            if (c < 360) {
                int k0 = c * 4;
                float v0 = (k0 + 0 < F_IN) ? Xr[k0 + 0] : 0.f;
                float v1 = (k0 + 1 < F_IN) ? Xr[k0 + 1] : 0.f;
                float v2 = (k0 + 2 < F_IN) ? Xr[k0 + 2] : 0.f;
                float v3 = (k0 + 3 < F_IN) ? Xr[k0 + 3] : 0.f;
                h4v o = {(_Float16)v0, (_Float16)v1, (_Float16)v2, (_Float16)v3};
                *(h4v*)(dst + k0) = o;
            }
        }
    }
    __syncthreads();

    // ---- barrier-free K-loop ----
    const _Float16* abase = xs + l15 * RST + k4r * 8;
    const _Float16* gb0 = W1S + (long)(k4r * 128 + w * 32 + l15) * 8;
    f4v acc0 = {0.f, 0.f, 0.f, 0.f}, acc1 = {0.f, 0.f, 0.f, 0.f};
#pragma unroll 5
    for (int s = 0; s < KSTEPS; ++s) {
        h8v av = *(const h8v*)(abase + s * 32);
        const _Float16* gb = gb0 + (long)s * 4096;
        h8v b0 = *(const h8v*)(gb);
        h8v b1 = *(const h8v*)(gb + 128);
        acc0 = __builtin_amdgcn_mfma_f32_16x16x32_f16(av, b0, acc0, 0, 0, 0);
        acc1 = __builtin_amdgcn_mfma_f32_16x16x32_f16(av, b1, acc1, 0, 0, 0);
    }

    // ---- epilogue: D row=(l>>4)*4+r, col=l&15; scale by nsrc, cast fp16 ----
    const int col = w * 32 + l15;
#pragma unroll
    for (int r = 0; r < 4; ++r) {
        int row = bm + (l >> 4) * 4 + r;
        float ns = nsrc[row];
        _Float16* hr = h + (long)row * HID + col;
        hr[0]  = (_Float16)(ns * acc0[r]);
        hr[16] = (_Float16)(ns * acc1[r]);
    }
}

// ---- agg1: 16-lane group per node, 4 rows per wave-load, unroll 8 ----
__global__ __launch_bounds__(256) void agg1_kernel(const _Float16* __restrict__ h,
                                                   const int* __restrict__ csr,
                                                   const int* __restrict__ rowptr,
                                                   const int* __restrict__ deg,
                                                   const float* __restrict__ ndst,
                                                   const float* __restrict__ nsrc,
                                                   const float* __restrict__ b1,
                                                   const float* __restrict__ W2,
                                                   float* __restrict__ h2p) {
    const int lane = threadIdx.x & 63;
    const int wave = threadIdx.x >> 6;
    const int fl = lane & 15;
    const int node = blockIdx.x * 16 + wave * 4 + (lane >> 4);
    const bool active = node < N_NODES;
    int p = active ? rowptr[node] : 0;
    int end = active ? p + deg[node] : 0;

    float acc[8];
#pragma unroll
    for (int j = 0; j < 8; j++) acc[j] = 0.f;
    const _Float16* hb = h + fl * 8;

    for (; p + 8 <= end; p += 8) {
        int i0 = csr[p], i1 = csr[p + 1], i2 = csr[p + 2], i3 = csr[p + 3];
        int i4 = csr[p + 4], i5 = csr[p + 5], i6 = csr[p + 6], i7 = csr[p + 7];
        h8v a0 = *(const h8v*)(hb + (long)i0 * HID);
        h8v a1 = *(const h8v*)(hb + (long)i1 * HID);
        h8v a2 = *(const h8v*)(hb + (long)i2 * HID);
        h8v a3 = *(const h8v*)(hb + (long)i3 * HID);
        h8v a4 = *(const h8v*)(hb + (long)i4 * HID);
        h8v a5 = *(const h8v*)(hb + (long)i5 * HID);
        h8v a6 = *(const h8v*)(hb + (long)i6 * HID);
        h8v a7 = *(const h8v*)(hb + (long)i7 * HID);
#pragma unroll
        for (int j = 0; j < 8; j++)
            acc[j] += (((float)a0[j] + (float)a1[j]) + ((float)a2[j] + (float)a3[j])) +
                      (((float)a4[j] + (float)a5[j]) + ((float)a6[j] + (float)a7[j]));
    }
    for (; p < end; ++p) {
        int i0 = csr[p];
        h8v a0 = *(const h8v*)(hb + (long)i0 * HID);
#pragma unroll
        for (int j = 0; j < 8; j++) acc[j] += (float)a0[j];
    }

    float nd = active ? ndst[node] : 0.f;
    float ns = active ? nsrc[node] : 0.f;
    float x[8];
#pragma unroll
    for (int j = 0; j < 8; j++)
        x[j] = fmaxf(acc[j] * nd + b1[fl * 8 + j], 0.f) * ns;

    float q[NCLS];
#pragma unroll
    for (int c = 0; c < NCLS; c++) {
        float s = 0.f;
#pragma unroll
        for (int j = 0; j < 8; j++) s += x[j] * W2[(fl * 8 + j) * NCLS + c];
        q[c] = s;
    }
#pragma unroll
    for (int c = 0; c < NCLS; c++) {
#pragma unroll
        for (int off = 1; off < 16; off <<= 1) q[c] += __shfl_xor(q[c], off);
    }
    if (active) {
        if (fl < NCLS) h2p[(long)node * 8 + fl] = q[fl];
        if (fl == 7) h2p[(long)node * 8 + 7] = 0.f;
    }
}

// per dst node: out = (sum h2[src]) * nd + b2  (h2 stride-8, 2x float4 per edge)
__global__ __launch_bounds__(256) void agg2_kernel(const float* __restrict__ h2p,
                                                   const int* __restrict__ csr,
                                                   const int* __restrict__ rowptr,
                                                   const int* __restrict__ deg,
                                                   const float* __restrict__ ndst,
                                                   const float* __restrict__ b2,
                                                   float* __restrict__ out) {
    int wid = threadIdx.x >> 6, lane = threadIdx.x & 63;
    int node = blockIdx.x * 4 + wid;
    if (node >= N_NODES) return;
    int rp = rowptr[node], end = rp + deg[node];
    float a0 = 0.f, a1 = 0.f, a2 = 0.f, a3 = 0.f, a4 = 0.f, a5 = 0.f, a6 = 0.f;
    for (int p = rp + lane; p < end; p += 64) {
        int s = csr[p];
        const float4* r = (const float4*)(h2p + (long)s * 8);
        float4 lo = r[0], hi = r[1];
        a0 += lo.x; a1 += lo.y; a2 += lo.z; a3 += lo.w;
        a4 += hi.x; a5 += hi.y; a6 += hi.z;
    }
    float nd = ndst[node];
    float acc[NCLS] = {a0, a1, a2, a3, a4, a5, a6};
#pragma unroll
    for (int c = 0; c < NCLS; c++) {
        float v = acc[c];
#pragma unroll
        for (int off = 1; off < 64; off <<= 1) v += __shfl_xor(v, off);
        if (lane == c) out[(long)node * NCLS + c] = v * nd + b2[c];
    }
}

extern "C" void kernel_launch(void* const* d_in, const int* in_sizes, int n_in,
                              void* d_out, int out_size, void* d_ws, size_t ws_size,
                              hipStream_t stream) {
    const float* X  = (const float*)d_in[0];
    const int* src  = (const int*)d_in[1];
    const int* dst  = (const int*)d_in[2];
    const float* W1 = (const float*)d_in[3];
    const float* b1 = (const float*)d_in[4];
    const float* W2 = (const float*)d_in[5];
    const float* b2 = (const float*)d_in[6];
    float* out = (float*)d_out;

    char* ws = (char*)d_ws;
    int* deg_src = (int*)(ws + O_DEG_SRC);
    int* deg_dst = (int*)(ws + O_DEG_DST);
    int* cursor  = (int*)(ws + O_CURSOR);
    int* rowptr  = (int*)(ws + O_ROWPTR);
    float* nsrc  = (float*)(ws + O_NSRC);
    float* ndst  = (float*)(ws + O_NDST);
    int* bsum    = (int*)(ws + O_BSUM);
    int* boff    = (int*)(ws + O_BOFF);
    int* csr     = (int*)(ws + O_CSR);
    _Float16* h  = (_Float16*)(ws + O_H);
    float* h2p   = (float*)(ws + O_H2);
    _Float16* W1S = (_Float16*)(ws + O_W1S);

    const int nb = (N_NODES + 255) / 256;  // 196
    zero_ws_kernel<<<147, 256, 0, stream>>>((int4*)ws);
    w1prep_kernel<<<(KSTEPS * 4 * 128 + 255) / 256, 256, 0, stream>>>(W1, W1S);
    deg_kernel<<<N_EDGES / 256, 256, 0, stream>>>(dst, deg_dst);
    scan1_kernel<<<nb, 256, 0, stream>>>(deg_dst, rowptr, bsum);
    scan2_kernel<<<1, 256, 0, stream>>>(bsum, boff, nb);
    scan3_kernel<<<nb, 256, 0, stream>>>(rowptr, deg_dst, boff, ndst);
    fill_kernel<<<N_EDGES / 256, 256, 0, stream>>>(src, dst, rowptr, cursor, csr, deg_src);
    nsrc_kernel<<<nb, 256, 0, stream>>>(deg_src, nsrc);

    gemm1_mfma_kernel<<<N_NODES / GBM, 256, 0, stream>>>(X, W1S, nsrc, h);

    agg1_kernel<<<(N_NODES + 15) / 16, 256, 0, stream>>>(h, csr, rowptr, deg_dst, ndst, nsrc,
                                                         b1, W2, h2p);
    agg2_kernel<<<(N_NODES + 3) / 4, 256, 0, stream>>>(h2p, csr, rowptr, deg_dst, ndst, b2, out);
}